// Round 12
// baseline (622.804 us; speedup 1.0000x reference)
//
#include <hip/hip_runtime.h>

#define NPTS 16384
#define CH 128
#define KNN 9
#define NCAND 12          // per column-quarter
#define NHALF 4           // column splits
#define COUT 256
#define RG 16             // refine: threads per point
#define RCAND 3           // refine: candidates per thread (48/16)

typedef __attribute__((ext_vector_type(8))) short bf16x8;
typedef __attribute__((ext_vector_type(4))) float f32x4;
typedef __attribute__((address_space(1))) const unsigned gu32;
typedef __attribute__((address_space(3))) unsigned lu32;

// Workspace budget: proven safe at 1.375 MiB (round 8); 2.125 MiB corrupted
// harness memory (round 10). d_ws layout: sq 64K + nbr 288K + Wt 256K = 608 KiB.
// Large scratch lives in d_out (16 MB fp32) — legal: harness re-poisons d_out
// each replay, we recompute every launch, out_kernel overwrites all of it last.
//   d_out[0      .. 4 MiB)  : xhi  (bf16 hi split, swizzled)
//   d_out[4 MiB  .. 5.5 MiB): cand (N * NHALF*NCAND u16)
//
// Round 25: knn is tuned out (conflicts 0, spill 0, 1 barrier/tile, 420 µs);
// the tail is out_kernel: thread=col made cat[i][c0] WAVE-UNIFORM, so each of
// 4 waves/block issued 2048 broadcast ds_read_b128 (4.2M total ~ 80+ µs LDS
// pipe) at a 2-blk/CU grid cap. Fix: 1-wave blocks of 8 rows (grid 2048,
// 8 waves/CU), thread = 4 cols {t+64c}, acc[8][4] -> LDS reads /4 (1M),
// W pre-transposed (wt_kernel, Wt[col][k], 256 KiB d_ws) so W loads are
// float4 along k. FMA order (c0 asc, k asc, bias first) byte-identical to
// the old out_kernel -> bit-identical output.

// bf16 RNE hi of a packed float pair (x0 low, x1 high).
__device__ __forceinline__ unsigned bfhi2(float x0, float x1) {
    unsigned u0 = __float_as_uint(x0), u1 = __float_as_uint(x1);
    unsigned r0 = (u0 + 0x7fffu + ((u0 >> 16) & 1u));
    unsigned r1 = (u1 + 0x7fffu + ((u1 >> 16) & 1u));
    return (r0 >> 16) | (r1 & 0xffff0000u);
}

// ---- Register-guaranteed top-k lists: named scalars only (no arrays!). ----
// LLVM SROA runs before loop unrolling, so loop-indexed private arrays stay in
// scratch (round 6/7: 5.4 GB scratch writes, VALUBusy 7%). (Fully-unrolled
// constant-index arrays like acc[8][4] DO promote — the hazard is dynamic
// indexing surviving unroll.)
struct TopL {
    float l0,l1,l2,l3,l4,l5,l6,l7,l8,l9,la,lb;
    int   m0,m1,m2,m3,m4,m5,m6,m7,m8,m9,ma,mb;
};
struct Top9 {
    float l0,l1,l2,l3,l4,l5,l6,l7,l8;
    int   m0,m1,m2,m3,m4,m5,m6,m7,m8;
};

__device__ __forceinline__ bool lexlt(float d, int g, float L, int M) {
    return d < L || (d == L && g < M);
}

__device__ __forceinline__ void ins12(TopL& T, float d, int g) {
    if (!lexlt(d, g, T.lb, T.mb)) return;
    bool b0 = lexlt(d,g,T.l0,T.m0);
    bool b1 = lexlt(d,g,T.l1,T.m1);
    bool b2 = lexlt(d,g,T.l2,T.m2);
    bool b3 = lexlt(d,g,T.l3,T.m3);
    bool b4 = lexlt(d,g,T.l4,T.m4);
    bool b5 = lexlt(d,g,T.l5,T.m5);
    bool b6 = lexlt(d,g,T.l6,T.m6);
    bool b7 = lexlt(d,g,T.l7,T.m7);
    bool b8 = lexlt(d,g,T.l8,T.m8);
    bool b9 = lexlt(d,g,T.l9,T.m9);
    bool ba = lexlt(d,g,T.la,T.ma);
    T.lb = ba ? T.la : d;               T.mb = ba ? T.ma : g;
    T.la = b9 ? T.l9 : (ba ? d : T.la); T.ma = b9 ? T.m9 : (ba ? g : T.ma);
    T.l9 = b8 ? T.l8 : (b9 ? d : T.l9); T.m9 = b8 ? T.m8 : (b9 ? g : T.m9);
    T.l8 = b7 ? T.l7 : (b8 ? d : T.l8); T.m8 = b7 ? T.m7 : (b8 ? g : T.m8);
    T.l7 = b6 ? T.l6 : (b7 ? d : T.l7); T.m7 = b6 ? T.m6 : (b7 ? g : T.m7);
    T.l6 = b5 ? T.l5 : (b6 ? d : T.l6); T.m6 = b5 ? T.m5 : (b6 ? g : T.m6);
    T.l5 = b4 ? T.l4 : (b5 ? d : T.l5); T.m5 = b4 ? T.m4 : (b5 ? g : T.m5);
    T.l4 = b3 ? T.l3 : (b4 ? d : T.l4); T.m4 = b3 ? T.m3 : (b4 ? g : T.m4);
    T.l3 = b2 ? T.l2 : (b3 ? d : T.l3); T.m3 = b2 ? T.m2 : (b3 ? g : T.m3);
    T.l2 = b1 ? T.l1 : (b2 ? d : T.l2); T.m2 = b1 ? T.m1 : (b2 ? g : T.m2);
    T.l1 = b0 ? T.l0 : (b1 ? d : T.l1); T.m1 = b0 ? T.m0 : (b1 ? g : T.m1);
    T.l0 = b0 ? d : T.l0;               T.m0 = b0 ? g : T.m0;
}

__device__ __forceinline__ void ins9(Top9& T, float d, int g) {
    if (!lexlt(d, g, T.l8, T.m8)) return;
    bool b0 = lexlt(d,g,T.l0,T.m0);
    bool b1 = lexlt(d,g,T.l1,T.m1);
    bool b2 = lexlt(d,g,T.l2,T.m2);
    bool b3 = lexlt(d,g,T.l3,T.m3);
    bool b4 = lexlt(d,g,T.l4,T.m4);
    bool b5 = lexlt(d,g,T.l5,T.m5);
    bool b6 = lexlt(d,g,T.l6,T.m6);
    bool b7 = lexlt(d,g,T.l7,T.m7);
    T.l8 = b7 ? T.l7 : d;               T.m8 = b7 ? T.m7 : g;
    T.l7 = b6 ? T.l6 : (b7 ? d : T.l7); T.m7 = b6 ? T.m6 : (b7 ? g : T.m7);
    T.l6 = b5 ? T.l5 : (b6 ? d : T.l6); T.m6 = b5 ? T.m5 : (b6 ? g : T.m6);
    T.l5 = b4 ? T.l4 : (b5 ? d : T.l5); T.m5 = b4 ? T.m4 : (b5 ? g : T.m5);
    T.l4 = b3 ? T.l3 : (b4 ? d : T.l4); T.m4 = b3 ? T.m3 : (b4 ? g : T.m4);
    T.l3 = b2 ? T.l2 : (b3 ? d : T.l3); T.m3 = b2 ? T.m2 : (b3 ? g : T.m3);
    T.l2 = b1 ? T.l1 : (b2 ? d : T.l2); T.m2 = b1 ? T.m1 : (b2 ? g : T.m2);
    T.l1 = b0 ? T.l0 : (b1 ? d : T.l1); T.m1 = b0 ? T.m0 : (b1 ? g : T.m1);
    T.l0 = b0 ? d : T.l0;               T.m0 = b0 ? g : T.m0;
}

__device__ __forceinline__ void merge_shfl(TopL& T, int mask) {
    TopL o;
    o.l0=__shfl_xor(T.l0,mask); o.m0=__shfl_xor(T.m0,mask);
    o.l1=__shfl_xor(T.l1,mask); o.m1=__shfl_xor(T.m1,mask);
    o.l2=__shfl_xor(T.l2,mask); o.m2=__shfl_xor(T.m2,mask);
    o.l3=__shfl_xor(T.l3,mask); o.m3=__shfl_xor(T.m3,mask);
    o.l4=__shfl_xor(T.l4,mask); o.m4=__shfl_xor(T.m4,mask);
    o.l5=__shfl_xor(T.l5,mask); o.m5=__shfl_xor(T.m5,mask);
    o.l6=__shfl_xor(T.l6,mask); o.m6=__shfl_xor(T.m6,mask);
    o.l7=__shfl_xor(T.l7,mask); o.m7=__shfl_xor(T.m7,mask);
    o.l8=__shfl_xor(T.l8,mask); o.m8=__shfl_xor(T.m8,mask);
    o.l9=__shfl_xor(T.l9,mask); o.m9=__shfl_xor(T.m9,mask);
    o.la=__shfl_xor(T.la,mask); o.ma=__shfl_xor(T.ma,mask);
    o.lb=__shfl_xor(T.lb,mask); o.mb=__shfl_xor(T.mb,mask);
    ins12(T,o.l0,o.m0); ins12(T,o.l1,o.m1); ins12(T,o.l2,o.m2);
    ins12(T,o.l3,o.m3); ins12(T,o.l4,o.m4); ins12(T,o.l5,o.m5);
    ins12(T,o.l6,o.m6); ins12(T,o.l7,o.m7); ins12(T,o.l8,o.m8);
    ins12(T,o.l9,o.m9); ins12(T,o.la,o.ma); ins12(T,o.lb,o.mb);
}

__device__ __forceinline__ void merge_shfl9(Top9& T, int mask) {
    Top9 o;
    o.l0=__shfl_xor(T.l0,mask); o.m0=__shfl_xor(T.m0,mask);
    o.l1=__shfl_xor(T.l1,mask); o.m1=__shfl_xor(T.m1,mask);
    o.l2=__shfl_xor(T.l2,mask); o.m2=__shfl_xor(T.m2,mask);
    o.l3=__shfl_xor(T.l3,mask); o.m3=__shfl_xor(T.m3,mask);
    o.l4=__shfl_xor(T.l4,mask); o.m4=__shfl_xor(T.m4,mask);
    o.l5=__shfl_xor(T.l5,mask); o.m5=__shfl_xor(T.m5,mask);
    o.l6=__shfl_xor(T.l6,mask); o.m6=__shfl_xor(T.m6,mask);
    o.l7=__shfl_xor(T.l7,mask); o.m7=__shfl_xor(T.m7,mask);
    o.l8=__shfl_xor(T.l8,mask); o.m8=__shfl_xor(T.m8,mask);
    ins9(T,o.l0,o.m0); ins9(T,o.l1,o.m1); ins9(T,o.l2,o.m2);
    ins9(T,o.l3,o.m3); ins9(T,o.l4,o.m4); ins9(T,o.l5,o.m5);
    ins9(T,o.l6,o.m6); ins9(T,o.l7,o.m7); ins9(T,o.l8,o.m8);
}

// ---------------- Kernel 1: numpy pairwise_sum replica of np.sum(x*x, -1) ----------------
// DO NOT TOUCH: this exact rounding order makes selection match the reference
// bit-for-bit (round 6, absmax 0.0).
__global__ __launch_bounds__(256) void sqnp_kernel(const float* __restrict__ x,
                                                   float* __restrict__ sq) {
    const int i = blockIdx.x * 256 + threadIdx.x;
    const float4* row4 = (const float4*)(x + (size_t)i * CH);
    float r[8];
    {
        float4 a = row4[0], b = row4[1];
        r[0] = __fmul_rn(a.x, a.x); r[1] = __fmul_rn(a.y, a.y);
        r[2] = __fmul_rn(a.z, a.z); r[3] = __fmul_rn(a.w, a.w);
        r[4] = __fmul_rn(b.x, b.x); r[5] = __fmul_rn(b.y, b.y);
        r[6] = __fmul_rn(b.z, b.z); r[7] = __fmul_rn(b.w, b.w);
    }
#pragma unroll
    for (int g = 1; g < 16; ++g) {
        float4 a = row4[2 * g], b = row4[2 * g + 1];
        r[0] = __fadd_rn(r[0], __fmul_rn(a.x, a.x));
        r[1] = __fadd_rn(r[1], __fmul_rn(a.y, a.y));
        r[2] = __fadd_rn(r[2], __fmul_rn(a.z, a.z));
        r[3] = __fadd_rn(r[3], __fmul_rn(a.w, a.w));
        r[4] = __fadd_rn(r[4], __fmul_rn(b.x, b.x));
        r[5] = __fadd_rn(r[5], __fmul_rn(b.y, b.y));
        r[6] = __fadd_rn(r[6], __fmul_rn(b.z, b.z));
        r[7] = __fadd_rn(r[7], __fmul_rn(b.w, b.w));
    }
    float t0 = __fadd_rn(__fadd_rn(r[0], r[1]), __fadd_rn(r[2], r[3]));
    float t1 = __fadd_rn(__fadd_rn(r[4], r[5]), __fadd_rn(r[6], r[7]));
    sq[i] = __fadd_rn(t0, t1);
}

// ---------- Kernel 1.5: one-shot fp32 -> bf16 hi split, swizzled tile layout -------
// Layout: xhi[r*128 + (s^(r&15))*8 + j] = hi(x[r][s*8+j]) — identical to the
// LDS physical layout, so knn staging copies physical slots 1:1.
__global__ __launch_bounds__(256) void split_kernel(const float* __restrict__ x,
                                                    short* __restrict__ xhi) {
    const int P = blockIdx.x * 256 + threadIdx.x;  // (row, slot): N*16 tasks
    const int r = P >> 4;
    const int s = P & 15;
    const int phys = s ^ (r & 15);
    const float4* src = (const float4*)(x + (size_t)r * CH) + s * 2;
    float4 f0 = src[0], f1 = src[1];
    uint4 h;
    h.x = bfhi2(f0.x, f0.y);
    h.y = bfhi2(f0.z, f0.w);
    h.z = bfhi2(f1.x, f1.y);
    h.w = bfhi2(f1.z, f1.w);
    *(uint4*)&xhi[(size_t)r * 128 + phys * 8] = h;
}

// ---------- Kernel 1.7: one-shot W transpose: Wt[col][k] = W[k][col] ----------
// Lets out_kernel load W as float4 along k. Read once, 256 KiB.
__global__ __launch_bounds__(256) void wt_kernel(const float* __restrict__ W,
                                                 float* __restrict__ Wt) {
    const int c = blockIdx.x;          // output column 0..255
    const int k = threadIdx.x;         // k index 0..255 (2*CH == 256)
    Wt[(size_t)c * (2 * CH) + k] = W[(size_t)k * COUT + c];
}

// ------------- Kernel 2: transposed hi-only MFMA distance-GEMM, in-register top-12 ----
// D[cand][query] = mfma(cand_frag, query_frag): lane (quad,m) accumulates
// cands {ct+cg*16+quad*4+reg} for query row0+16w+m. Selection on acc regs.
// Double-buffered Bhi (2 x 16 KiB): ONE barrier/tile; prefetch issued before
// the MFMA phase, in flight across MFMA+selection, drained at next loop-top.
__global__ __launch_bounds__(256, 3) void knn_kernel(const short* __restrict__ xhi,
                                                     const float* __restrict__ sq,
                                                     unsigned short* __restrict__ cand) {
    __shared__ short Bhi[2 * 64 * 128];
    const int t = threadIdx.x;
    const int row0 = blockIdx.x * 64;
    const int half = blockIdx.y;
    const int ctbeg = half * (NPTS / NHALF);
    const int ctend = ctbeg + NPTS / NHALF;

    const int lane = t & 63;
    const int w = t >> 6;          // wave id: queries [row0+16w, +16)
    const int m = lane & 15;
    const int quad = lane >> 4;

    // ---- prologue: async-stage first B tile into buffer 0 ----
#pragma unroll
    for (int it = 0; it < 4; ++it) {
        const int P = t + it * 256;  // physical (row, slot)
        __builtin_amdgcn_global_load_lds(
            (gu32*)&xhi[(size_t)ctbeg * 128 + P * 8],
            (lu32*)&Bhi[(it * 256 + w * 64) * 8], 16, 0, 0);
    }
    // Query row r = row0+16w+m has r&15 == m, so physical slot (kc*4+quad)^m
    // holds logical k-chunk (kc, quad) — B-fragment col=lane&15, k=8*quad+j.
    const short* qrow = xhi + (size_t)(row0 + 16 * w + m) * 128;
    const bf16x8 a0 = *(const bf16x8*)&qrow[((0 * 4 + quad) ^ m) * 8];
    const bf16x8 a1 = *(const bf16x8*)&qrow[((1 * 4 + quad) ^ m) * 8];
    const bf16x8 a2 = *(const bf16x8*)&qrow[((2 * 4 + quad) ^ m) * 8];
    const bf16x8 a3 = *(const bf16x8*)&qrow[((3 * 4 + quad) ^ m) * 8];

    TopL T;
    T.l0=T.l1=T.l2=T.l3=T.l4=T.l5=T.l6=T.l7=T.l8=T.l9=T.la=T.lb = __builtin_inff();
    T.m0=T.m1=T.m2=T.m3=T.m4=T.m5=T.m6=T.m7=T.m8=T.m9=T.ma=T.mb = 0x7fffffff;

    const int qglob = row0 + 16 * w + m;   // this lane's query (per-lane list)

    // cross-tile persistent pass-queue (flushed on wave-any overflow)
    float qd0 = __builtin_inff(), qd1 = __builtin_inff();
    int   qg0 = 0x7fffffff,      qg1 = 0x7fffffff;
    int   qn = 0;

    int boff = 0;                  // current B buffer element offset (0 / 8192)
    for (int ct = ctbeg; ct < ctend; ct += 64) {
        __syncthreads();           // drains vmcnt: B(ct) fully in buf[boff]

        const short* Bc = Bhi + boff;
        short* Bn = Bhi + (boff ^ (64 * 128));

        // ---- async-prefetch next tile into the OTHER buffer, BEFORE the MFMA
        // phase: loads in flight across MFMA+selection; next barrier drains.
        const int ctn = ct + 64;
        if (ctn < ctend) {
#pragma unroll
            for (int it = 0; it < 4; ++it) {
                const int P = t + it * 256;
                __builtin_amdgcn_global_load_lds(
                    (gu32*)&xhi[(size_t)ctn * 128 + P * 8],
                    (lu32*)&Bn[(it * 256 + w * 64) * 8], 16, 0, 0);
            }
        }

        f32x4 acc0 = {0.f,0.f,0.f,0.f};
        f32x4 acc1 = {0.f,0.f,0.f,0.f};
        f32x4 acc2 = {0.f,0.f,0.f,0.f};
        f32x4 acc3 = {0.f,0.f,0.f,0.f};

#pragma unroll
        for (int kc = 0; kc < 4; ++kc) {
            const int ks = ((kc * 4 + quad) ^ m) * 8;
            const bf16x8 ah = (kc == 0) ? a0 : (kc == 1) ? a1 : (kc == 2) ? a2 : a3;
            bf16x8 bh0 = *(const bf16x8*)&Bc[(0  + m) * 128 + ks];
            bf16x8 bh1 = *(const bf16x8*)&Bc[(16 + m) * 128 + ks];
            bf16x8 bh2 = *(const bf16x8*)&Bc[(32 + m) * 128 + ks];
            bf16x8 bh3 = *(const bf16x8*)&Bc[(48 + m) * 128 + ks];
            // TRANSPOSED: cand fragments as A, query fragment as B.
            acc0 = __builtin_amdgcn_mfma_f32_16x16x32_bf16(bh0, ah, acc0, 0, 0, 0);
            acc1 = __builtin_amdgcn_mfma_f32_16x16x32_bf16(bh1, ah, acc1, 0, 0, 0);
            acc2 = __builtin_amdgcn_mfma_f32_16x16x32_bf16(bh2, ah, acc2, 0, 0, 0);
            acc3 = __builtin_amdgcn_mfma_f32_16x16x32_bf16(bh3, ah, acc3, 0, 0, 0);
        }
        // no second barrier: prefetch targets the other buffer; Bc is stable
        // until every wave passes the NEXT loop-top barrier.

        // ---- in-register selection: lane holds D[cand][qglob] for 16 cands.
        // d = sq[cand] - 2*dot; sq[query] omitted (constant per lane's list).
        // Relaxed threshold d <= lb; persistent 2-deep queue; overflow
        // passers insert immediately — every passer reaches ins12 once.
#pragma unroll
        for (int cg = 0; cg < 4; ++cg) {
            const f32x4 ac = (cg == 0) ? acc0 : (cg == 1) ? acc1
                           : (cg == 2) ? acc2 : acc3;
            const float4 s4 = *(const float4*)&sq[ct + cg * 16 + quad * 4];
#pragma unroll
            for (int reg = 0; reg < 4; ++reg) {
                const float sv = (reg == 0) ? s4.x : (reg == 1) ? s4.y
                               : (reg == 2) ? s4.z : s4.w;
                const float d = __builtin_fmaf(-2.f, ac[reg], sv);
                const int cgi = ct + cg * 16 + quad * 4 + reg;
                const bool pass = (d <= T.lb) && (cgi != qglob);
                if (pass) {
                    if (qn >= 2) {
                        ins12(T, d, cgi);
                    } else if (qn == 0) {
                        qd0 = d; qg0 = cgi;
                    } else {
                        qd1 = d; qg1 = cgi;
                    }
                    ++qn;
                }
            }
        }
        // flush only when some lane's queue is full — wave-uniform branch
        if (__any(qn >= 2)) {
            ins12(T, qd0, qg0);
            ins12(T, qd1, qg1);
            qd0 = qd1 = __builtin_inff();
            qg0 = qg1 = 0x7fffffff;
            qn = 0;
        }
        boff ^= 64 * 128;
    }

    // final queue flush (inf entries are no-ops), then merge the 4 partial
    // lists per query (lanes m, m+16, m+32, m+48 share query m)
    ins12(T, qd0, qg0);
    ins12(T, qd1, qg1);
    merge_shfl(T, 16);
    merge_shfl(T, 32);

    if (quad == 0) {
        unsigned short* cp_out = cand + (size_t)qglob * (NHALF * NCAND) + half * NCAND;
        cp_out[0]=(unsigned short)T.m0; cp_out[1]=(unsigned short)T.m1;
        cp_out[2]=(unsigned short)T.m2; cp_out[3]=(unsigned short)T.m3;
        cp_out[4]=(unsigned short)T.m4; cp_out[5]=(unsigned short)T.m5;
        cp_out[6]=(unsigned short)T.m6; cp_out[7]=(unsigned short)T.m7;
        cp_out[8]=(unsigned short)T.m8; cp_out[9]=(unsigned short)T.m9;
        cp_out[10]=(unsigned short)T.ma; cp_out[11]=(unsigned short)T.mb;
    }
}

// ---------------- Kernel 2.5: numpy-fp32-replica re-rank of 48 candidates ----------------
// 16 threads/point (3 cands each), shfl-merge of partial Top9s — top-k under the
// (d, idx) lexicographic total order is order-independent, so the split is exact.
// dot: BLAS sgemm per-element rounding = ONE accumulator, sequential ascending-k FMA.
// d  : fl( fl(sq_i + sq_j) - fl(2*dot) ).
// DO NOT TOUCH the rounding order — verified exact vs reference (round 6, absmax 0.0).
__global__ __launch_bounds__(256) void refine_np_kernel(const float* __restrict__ x,
                                                        const float* __restrict__ sq,
                                                        const unsigned short* __restrict__ cand,
                                                        unsigned short* __restrict__ nbr) {
    const int gt = blockIdx.x * 256 + threadIdx.x;
    const int i = gt >> 4;         // point
    const int g = gt & (RG - 1);   // candidate group
    const float4* X4 = (const float4*)x;
    const float sqi = sq[i];

    int ci[RCAND];
#pragma unroll
    for (int m = 0; m < RCAND; ++m)
        ci[m] = (int)cand[i * (NHALF * NCAND) + g * RCAND + m];
    float dot[RCAND];
#pragma unroll
    for (int m = 0; m < RCAND; ++m) dot[m] = 0.f;
#pragma unroll 4
    for (int c4 = 0; c4 < 32; ++c4) {
        float4 xv = X4[(size_t)i * 32 + c4];
#pragma unroll
        for (int m = 0; m < RCAND; ++m) {
            float4 nv = X4[(size_t)ci[m] * 32 + c4];
            float a = dot[m];
            a = __builtin_fmaf(xv.x, nv.x, a);
            a = __builtin_fmaf(xv.y, nv.y, a);
            a = __builtin_fmaf(xv.z, nv.z, a);
            a = __builtin_fmaf(xv.w, nv.w, a);
            dot[m] = a;
        }
    }

    Top9 T;
    T.l0=T.l1=T.l2=T.l3=T.l4=T.l5=T.l6=T.l7=T.l8 = __builtin_inff();
    T.m0=T.m1=T.m2=T.m3=T.m4=T.m5=T.m6=T.m7=T.m8 = 0x7fffffff;
#pragma unroll
    for (int m = 0; m < RCAND; ++m) {
        float s = __fadd_rn(sqi, sq[ci[m]]);
        float d = __fsub_rn(s, __fmul_rn(2.0f, dot[m]));
        ins9(T, d, ci[m]);
    }

    // merge the 16 partial lists per point (lanes g^1,g^2,g^4,g^8 share point i)
    merge_shfl9(T, 1);
    merge_shfl9(T, 2);
    merge_shfl9(T, 4);
    merge_shfl9(T, 8);

    if (g == 0) {
        unsigned short* np = nbr + (size_t)i * KNN;
        np[0]=(unsigned short)T.m0; np[1]=(unsigned short)T.m1; np[2]=(unsigned short)T.m2;
        np[3]=(unsigned short)T.m3; np[4]=(unsigned short)T.m4; np[5]=(unsigned short)T.m5;
        np[6]=(unsigned short)T.m6; np[7]=(unsigned short)T.m7; np[8]=(unsigned short)T.m8;
    }
}

// ---------------- Kernel 3: rel-pos add + max-relative + concat-GEMM ----------------
// 1-wave blocks of 8 rows (grid 2048, 8 waves/CU): cat reads are broadcast and
// now issued by ONE wave per block (LDS instr total /4 vs the 4-wave layout).
// Thread t owns cols {t, t+64, t+128, t+192}; W read via Wt float4 along k.
// FMA order (c0 asc, k asc, bias first) identical to the old version ->
// bit-identical output.
__global__ __launch_bounds__(64) void out_kernel(const float* __restrict__ x,
                                                 const float* __restrict__ tab,
                                                 const float* __restrict__ Wt,
                                                 const float* __restrict__ bias,
                                                 const unsigned short* __restrict__ nbr,
                                                 float* __restrict__ out) {
    __shared__ float cat[8][260];
    const int t = threadIdx.x;
    const int row0 = blockIdx.x * 8;
    {
        const int row = t >> 3;
        const int q = t & 7;
        const int i = row0 + row;
        const int rel_i = (i >> 7) - (i & 127) + 127;
        int nb[KNN], reln[KNN];
#pragma unroll
        for (int j = 0; j < KNN; ++j) {
            nb[j] = (int)nbr[i * KNN + j];
            reln[j] = (nb[j] >> 7) - (nb[j] & 127) + 127;
        }
        const float4* X4 = (const float4*)x;
        const float4* T4 = (const float4*)tab;
#pragma unroll
        for (int cc = 0; cc < 4; ++cc) {
            const int c4 = q * 4 + cc;
            float4 xv = X4[i * 32 + c4];
            float4 tv = T4[rel_i * 32 + c4];
            float4 xi;
            xi.x = xv.x + tv.x; xi.y = xv.y + tv.y; xi.z = xv.z + tv.z; xi.w = xv.w + tv.w;
            const float ninf = -__builtin_inff();
            float4 mx = {ninf, ninf, ninf, ninf};
#pragma unroll
            for (int j = 0; j < KNN; ++j) {
                float4 nv = X4[nb[j] * 32 + c4];
                float4 ntv = T4[reln[j] * 32 + c4];
                mx.x = fmaxf(mx.x, nv.x + ntv.x - xi.x);
                mx.y = fmaxf(mx.y, nv.y + ntv.y - xi.y);
                mx.z = fmaxf(mx.z, nv.z + ntv.z - xi.z);
                mx.w = fmaxf(mx.w, nv.w + ntv.w - xi.w);
            }
            *(float4*)&cat[row][c4 * 4] = xi;
            *(float4*)&cat[row][CH + c4 * 4] = mx;
        }
    }
    __syncthreads();

    float acc[8][4];
#pragma unroll
    for (int c = 0; c < 4; ++c) {
        const float bo = bias[t + 64 * c];
#pragma unroll
        for (int i = 0; i < 8; ++i) acc[i][c] = bo;
    }

    const float4* WT4 = (const float4*)Wt;   // Wt[col][k], k vectorized
#pragma unroll 2
    for (int c04 = 0; c04 < 64; ++c04) {     // c0 = 4*c04
        float4 wv0 = WT4[(size_t)(t +   0) * 64 + c04];
        float4 wv1 = WT4[(size_t)(t +  64) * 64 + c04];
        float4 wv2 = WT4[(size_t)(t + 128) * 64 + c04];
        float4 wv3 = WT4[(size_t)(t + 192) * 64 + c04];
#pragma unroll
        for (int i = 0; i < 8; ++i) {
            const float4 cv = *(const float4*)&cat[i][c04 * 4];
            acc[i][0] = fmaf(cv.x, wv0.x, acc[i][0]);
            acc[i][0] = fmaf(cv.y, wv0.y, acc[i][0]);
            acc[i][0] = fmaf(cv.z, wv0.z, acc[i][0]);
            acc[i][0] = fmaf(cv.w, wv0.w, acc[i][0]);
            acc[i][1] = fmaf(cv.x, wv1.x, acc[i][1]);
            acc[i][1] = fmaf(cv.y, wv1.y, acc[i][1]);
            acc[i][1] = fmaf(cv.z, wv1.z, acc[i][1]);
            acc[i][1] = fmaf(cv.w, wv1.w, acc[i][1]);
            acc[i][2] = fmaf(cv.x, wv2.x, acc[i][2]);
            acc[i][2] = fmaf(cv.y, wv2.y, acc[i][2]);
            acc[i][2] = fmaf(cv.z, wv2.z, acc[i][2]);
            acc[i][2] = fmaf(cv.w, wv2.w, acc[i][2]);
            acc[i][3] = fmaf(cv.x, wv3.x, acc[i][3]);
            acc[i][3] = fmaf(cv.y, wv3.y, acc[i][3]);
            acc[i][3] = fmaf(cv.z, wv3.z, acc[i][3]);
            acc[i][3] = fmaf(cv.w, wv3.w, acc[i][3]);
        }
    }

#pragma unroll
    for (int i = 0; i < 8; ++i) {
#pragma unroll
        for (int c = 0; c < 4; ++c) {
            out[(size_t)(row0 + i) * COUT + t + 64 * c] = acc[i][c];
        }
    }
}

extern "C" void kernel_launch(void* const* d_in, const int* in_sizes, int n_in,
                              void* d_out, int out_size, void* d_ws, size_t ws_size,
                              hipStream_t stream) {
    (void)in_sizes; (void)n_in; (void)out_size; (void)ws_size;
    const float* x = (const float*)d_in[0];
    const float* tab = (const float*)d_in[1];
    const float* W = (const float*)d_in[2];
    const float* b = (const float*)d_in[3];
    float* out = (float*)d_out;

    char* ws = (char*)d_ws;
    float* sq = (float*)ws;                                       // 64 KB
    unsigned short* nbr = (unsigned short*)(sq + NPTS);           // N*9 u16 = 288 KB
    float* Wt = (float*)(ws + 64 * 1024 + 288 * 1024);            // 256 KB
    // d_ws total 608 KiB < 1.375 MiB proven-safe (round 8)

    // d_out scratch (16 MB fp32): xhi 4 MB @0, cand 1.5 MB @4 MB.
    // Both recomputed every launch; out_kernel overwrites all of d_out last.
    short* xhi = (short*)d_out;
    unsigned short* cand = (unsigned short*)((char*)d_out + ((size_t)NPTS * CH * 2));

    sqnp_kernel<<<NPTS / 256, 256, 0, stream>>>(x, sq);
    split_kernel<<<NPTS * 16 / 256, 256, 0, stream>>>(x, xhi);
    wt_kernel<<<COUT, 2 * CH, 0, stream>>>(W, Wt);
    knn_kernel<<<dim3(NPTS / 64, NHALF), 256, 0, stream>>>(xhi, sq, cand);
    refine_np_kernel<<<NPTS * RG / 256, 256, 0, stream>>>(x, sq, cand, nbr);
    out_kernel<<<NPTS / 8, 64, 0, stream>>>(x, tab, Wt, b, nbr, out);
}

// Round 13
// 610.348 us; speedup vs baseline: 1.0204x; 1.0204x over previous
//
#include <hip/hip_runtime.h>

#define NPTS 16384
#define CH 128
#define KNN 9
#define NCAND 12          // per column-quarter
#define NHALF 4           // column splits
#define COUT 256
#define RG 16             // refine: threads per point
#define RCAND 3           // refine: candidates per thread (48/16)

typedef __attribute__((ext_vector_type(8))) short bf16x8;
typedef __attribute__((ext_vector_type(4))) float f32x4;
typedef __attribute__((address_space(1))) const unsigned gu32;
typedef __attribute__((address_space(3))) unsigned lu32;
typedef unsigned long long u64;

// Workspace budget: proven safe at 1.375 MiB (round 8); 2.125 MiB corrupted
// harness memory (round 10). d_ws layout: sq 64K + nbr 288K + Wt 256K = 608 KiB.
// Large scratch lives in d_out (16 MB fp32) — legal: harness re-poisons d_out
// each replay, we recompute every launch, out_kernel overwrites all of it last.
//   d_out[0      .. 4 MiB)  : xhi  (bf16 hi split, swizzled)
//   d_out[4 MiB  .. 5.5 MiB): cand (N * NHALF*NCAND u16)
//
// Round 26: VALU accounting showed ~1100 instr/wave-tile vs ~350 source-level
// — the (float,int) lexicographic top-k machinery is the gap (8 ops/level in
// ins12, fired via flush ~every tile). Fix: SORTABLE-U64 KEYS everywhere:
// key = (signflip(bits(d)) << 16) | idx. Strictly monotone in d (no -0.0:
// sqc >= 0), idx (16 bits, N < 2^14) breaks ties — order BIT-IDENTICAL to
// (d, idx) lex, so candidate sets (and absmax 0.0) are preserved. ins12 level:
// v_cmp_lt_u64 + 2 cndmask (~3 ops vs ~8); ins9 ditto; scan test = 1 u64 cmp;
// shfl merges halve. Same VGPR footprint (12 u64 = 24 regs).

// bf16 RNE hi of a packed float pair (x0 low, x1 high).
__device__ __forceinline__ unsigned bfhi2(float x0, float x1) {
    unsigned u0 = __float_as_uint(x0), u1 = __float_as_uint(x1);
    unsigned r0 = (u0 + 0x7fffu + ((u0 >> 16) & 1u));
    unsigned r1 = (u1 + 0x7fffu + ((u1 >> 16) & 1u));
    return (r0 >> 16) | (r1 & 0xffff0000u);
}

// Sortable key: strictly monotone float->u32 bit map, idx in low 16 bits.
__device__ __forceinline__ u64 mkkey(float d, int idx) {
    unsigned b = __float_as_uint(d);
    unsigned s = b ^ ((unsigned)((int)b >> 31) | 0x80000000u);
    return ((u64)s << 16) | (unsigned)idx;
}

// ---- Register-guaranteed top-k lists: named scalars only (no arrays!). ----
// LLVM SROA runs before loop unrolling, so loop-indexed private arrays stay in
// scratch (round 6/7: 5.4 GB scratch writes, VALUBusy 7%). (Fully-unrolled
// constant-index arrays like acc[8][4] DO promote — the hazard is dynamic
// indexing surviving unroll.)
struct TopK12 {
    u64 k0,k1,k2,k3,k4,k5,k6,k7,k8,k9,ka,kb;
};
struct TopK9 {
    u64 k0,k1,k2,k3,k4,k5,k6,k7,k8;
};

__device__ __forceinline__ void ins12(TopK12& T, u64 k) {
    if (k >= T.kb) return;
    bool b0 = k < T.k0;
    bool b1 = k < T.k1;
    bool b2 = k < T.k2;
    bool b3 = k < T.k3;
    bool b4 = k < T.k4;
    bool b5 = k < T.k5;
    bool b6 = k < T.k6;
    bool b7 = k < T.k7;
    bool b8 = k < T.k8;
    bool b9 = k < T.k9;
    bool ba = k < T.ka;
    T.kb = ba ? T.ka : k;
    T.ka = b9 ? T.k9 : (ba ? k : T.ka);
    T.k9 = b8 ? T.k8 : (b9 ? k : T.k9);
    T.k8 = b7 ? T.k7 : (b8 ? k : T.k8);
    T.k7 = b6 ? T.k6 : (b7 ? k : T.k7);
    T.k6 = b5 ? T.k5 : (b6 ? k : T.k6);
    T.k5 = b4 ? T.k4 : (b5 ? k : T.k5);
    T.k4 = b3 ? T.k3 : (b4 ? k : T.k4);
    T.k3 = b2 ? T.k2 : (b3 ? k : T.k3);
    T.k2 = b1 ? T.k1 : (b2 ? k : T.k2);
    T.k1 = b0 ? T.k0 : (b1 ? k : T.k1);
    T.k0 = b0 ? k : T.k0;
}

__device__ __forceinline__ void ins9(TopK9& T, u64 k) {
    if (k >= T.k8) return;
    bool b0 = k < T.k0;
    bool b1 = k < T.k1;
    bool b2 = k < T.k2;
    bool b3 = k < T.k3;
    bool b4 = k < T.k4;
    bool b5 = k < T.k5;
    bool b6 = k < T.k6;
    bool b7 = k < T.k7;
    T.k8 = b7 ? T.k7 : k;
    T.k7 = b6 ? T.k6 : (b7 ? k : T.k7);
    T.k6 = b5 ? T.k5 : (b6 ? k : T.k6);
    T.k5 = b4 ? T.k4 : (b5 ? k : T.k5);
    T.k4 = b3 ? T.k3 : (b4 ? k : T.k4);
    T.k3 = b2 ? T.k2 : (b3 ? k : T.k3);
    T.k2 = b1 ? T.k1 : (b2 ? k : T.k2);
    T.k1 = b0 ? T.k0 : (b1 ? k : T.k1);
    T.k0 = b0 ? k : T.k0;
}

__device__ __forceinline__ void merge_shfl(TopK12& T, int mask) {
    u64 o0=__shfl_xor(T.k0,mask), o1=__shfl_xor(T.k1,mask), o2=__shfl_xor(T.k2,mask);
    u64 o3=__shfl_xor(T.k3,mask), o4=__shfl_xor(T.k4,mask), o5=__shfl_xor(T.k5,mask);
    u64 o6=__shfl_xor(T.k6,mask), o7=__shfl_xor(T.k7,mask), o8=__shfl_xor(T.k8,mask);
    u64 o9=__shfl_xor(T.k9,mask), oa=__shfl_xor(T.ka,mask), ob=__shfl_xor(T.kb,mask);
    ins12(T,o0); ins12(T,o1); ins12(T,o2); ins12(T,o3);
    ins12(T,o4); ins12(T,o5); ins12(T,o6); ins12(T,o7);
    ins12(T,o8); ins12(T,o9); ins12(T,oa); ins12(T,ob);
}

__device__ __forceinline__ void merge_shfl9(TopK9& T, int mask) {
    u64 o0=__shfl_xor(T.k0,mask), o1=__shfl_xor(T.k1,mask), o2=__shfl_xor(T.k2,mask);
    u64 o3=__shfl_xor(T.k3,mask), o4=__shfl_xor(T.k4,mask), o5=__shfl_xor(T.k5,mask);
    u64 o6=__shfl_xor(T.k6,mask), o7=__shfl_xor(T.k7,mask), o8=__shfl_xor(T.k8,mask);
    ins9(T,o0); ins9(T,o1); ins9(T,o2); ins9(T,o3);
    ins9(T,o4); ins9(T,o5); ins9(T,o6); ins9(T,o7); ins9(T,o8);
}

// ---------------- Kernel 1: numpy pairwise_sum replica of np.sum(x*x, -1) ----------------
// DO NOT TOUCH: this exact rounding order makes selection match the reference
// bit-for-bit (round 6, absmax 0.0).
__global__ __launch_bounds__(256) void sqnp_kernel(const float* __restrict__ x,
                                                   float* __restrict__ sq) {
    const int i = blockIdx.x * 256 + threadIdx.x;
    const float4* row4 = (const float4*)(x + (size_t)i * CH);
    float r[8];
    {
        float4 a = row4[0], b = row4[1];
        r[0] = __fmul_rn(a.x, a.x); r[1] = __fmul_rn(a.y, a.y);
        r[2] = __fmul_rn(a.z, a.z); r[3] = __fmul_rn(a.w, a.w);
        r[4] = __fmul_rn(b.x, b.x); r[5] = __fmul_rn(b.y, b.y);
        r[6] = __fmul_rn(b.z, b.z); r[7] = __fmul_rn(b.w, b.w);
    }
#pragma unroll
    for (int g = 1; g < 16; ++g) {
        float4 a = row4[2 * g], b = row4[2 * g + 1];
        r[0] = __fadd_rn(r[0], __fmul_rn(a.x, a.x));
        r[1] = __fadd_rn(r[1], __fmul_rn(a.y, a.y));
        r[2] = __fadd_rn(r[2], __fmul_rn(a.z, a.z));
        r[3] = __fadd_rn(r[3], __fmul_rn(a.w, a.w));
        r[4] = __fadd_rn(r[4], __fmul_rn(b.x, b.x));
        r[5] = __fadd_rn(r[5], __fmul_rn(b.y, b.y));
        r[6] = __fadd_rn(r[6], __fmul_rn(b.z, b.z));
        r[7] = __fadd_rn(r[7], __fmul_rn(b.w, b.w));
    }
    float t0 = __fadd_rn(__fadd_rn(r[0], r[1]), __fadd_rn(r[2], r[3]));
    float t1 = __fadd_rn(__fadd_rn(r[4], r[5]), __fadd_rn(r[6], r[7]));
    sq[i] = __fadd_rn(t0, t1);
}

// ---------- Kernel 1.5: one-shot fp32 -> bf16 hi split, swizzled tile layout -------
// Layout: xhi[r*128 + (s^(r&15))*8 + j] = hi(x[r][s*8+j]) — identical to the
// LDS physical layout, so knn staging copies physical slots 1:1.
__global__ __launch_bounds__(256) void split_kernel(const float* __restrict__ x,
                                                    short* __restrict__ xhi) {
    const int P = blockIdx.x * 256 + threadIdx.x;  // (row, slot): N*16 tasks
    const int r = P >> 4;
    const int s = P & 15;
    const int phys = s ^ (r & 15);
    const float4* src = (const float4*)(x + (size_t)r * CH) + s * 2;
    float4 f0 = src[0], f1 = src[1];
    uint4 h;
    h.x = bfhi2(f0.x, f0.y);
    h.y = bfhi2(f0.z, f0.w);
    h.z = bfhi2(f1.x, f1.y);
    h.w = bfhi2(f1.z, f1.w);
    *(uint4*)&xhi[(size_t)r * 128 + phys * 8] = h;
}

// ---------- Kernel 1.7: one-shot W transpose: Wt[col][k] = W[k][col] ----------
// Lets out_kernel load W as float4 along k. Read once, 256 KiB.
__global__ __launch_bounds__(256) void wt_kernel(const float* __restrict__ W,
                                                 float* __restrict__ Wt) {
    const int c = blockIdx.x;          // output column 0..255
    const int k = threadIdx.x;         // k index 0..255 (2*CH == 256)
    Wt[(size_t)c * (2 * CH) + k] = W[(size_t)k * COUT + c];
}

// ------------- Kernel 2: transposed hi-only MFMA distance-GEMM, in-register top-12 ----
// D[cand][query] = mfma(cand_frag, query_frag): lane (quad,m) accumulates
// cands {ct+cg*16+quad*4+reg} for query row0+16w+m. Selection on acc regs
// with u64 keys. Double-buffered Bhi (2 x 16 KiB): ONE barrier/tile; prefetch
// issued before the MFMA phase, drained at next loop-top.
__global__ __launch_bounds__(256, 3) void knn_kernel(const short* __restrict__ xhi,
                                                     const float* __restrict__ sq,
                                                     unsigned short* __restrict__ cand) {
    __shared__ short Bhi[2 * 64 * 128];
    const int t = threadIdx.x;
    const int row0 = blockIdx.x * 64;
    const int half = blockIdx.y;
    const int ctbeg = half * (NPTS / NHALF);
    const int ctend = ctbeg + NPTS / NHALF;

    const int lane = t & 63;
    const int w = t >> 6;          // wave id: queries [row0+16w, +16)
    const int m = lane & 15;
    const int quad = lane >> 4;

    // ---- prologue: async-stage first B tile into buffer 0 ----
#pragma unroll
    for (int it = 0; it < 4; ++it) {
        const int P = t + it * 256;  // physical (row, slot)
        __builtin_amdgcn_global_load_lds(
            (gu32*)&xhi[(size_t)ctbeg * 128 + P * 8],
            (lu32*)&Bhi[(it * 256 + w * 64) * 8], 16, 0, 0);
    }
    // Query row r = row0+16w+m has r&15 == m, so physical slot (kc*4+quad)^m
    // holds logical k-chunk (kc, quad) — B-fragment col=lane&15, k=8*quad+j.
    const short* qrow = xhi + (size_t)(row0 + 16 * w + m) * 128;
    const bf16x8 a0 = *(const bf16x8*)&qrow[((0 * 4 + quad) ^ m) * 8];
    const bf16x8 a1 = *(const bf16x8*)&qrow[((1 * 4 + quad) ^ m) * 8];
    const bf16x8 a2 = *(const bf16x8*)&qrow[((2 * 4 + quad) ^ m) * 8];
    const bf16x8 a3 = *(const bf16x8*)&qrow[((3 * 4 + quad) ^ m) * 8];

    TopK12 T;
    T.k0=T.k1=T.k2=T.k3=T.k4=T.k5=T.k6=T.k7=T.k8=T.k9=T.ka=T.kb = ~0ULL;

    const int qglob = row0 + 16 * w + m;   // this lane's query (per-lane list)

    // cross-tile persistent pass-queue (flushed on wave-any overflow)
    u64 qk0 = ~0ULL, qk1 = ~0ULL;
    int qn = 0;

    int boff = 0;                  // current B buffer element offset (0 / 8192)
    for (int ct = ctbeg; ct < ctend; ct += 64) {
        __syncthreads();           // drains vmcnt: B(ct) fully in buf[boff]

        const short* Bc = Bhi + boff;
        short* Bn = Bhi + (boff ^ (64 * 128));

        // ---- async-prefetch next tile into the OTHER buffer, BEFORE the MFMA
        // phase: loads in flight across MFMA+selection; next barrier drains.
        const int ctn = ct + 64;
        if (ctn < ctend) {
#pragma unroll
            for (int it = 0; it < 4; ++it) {
                const int P = t + it * 256;
                __builtin_amdgcn_global_load_lds(
                    (gu32*)&xhi[(size_t)ctn * 128 + P * 8],
                    (lu32*)&Bn[(it * 256 + w * 64) * 8], 16, 0, 0);
            }
        }

        f32x4 acc0 = {0.f,0.f,0.f,0.f};
        f32x4 acc1 = {0.f,0.f,0.f,0.f};
        f32x4 acc2 = {0.f,0.f,0.f,0.f};
        f32x4 acc3 = {0.f,0.f,0.f,0.f};

#pragma unroll
        for (int kc = 0; kc < 4; ++kc) {
            const int ks = ((kc * 4 + quad) ^ m) * 8;
            const bf16x8 ah = (kc == 0) ? a0 : (kc == 1) ? a1 : (kc == 2) ? a2 : a3;
            bf16x8 bh0 = *(const bf16x8*)&Bc[(0  + m) * 128 + ks];
            bf16x8 bh1 = *(const bf16x8*)&Bc[(16 + m) * 128 + ks];
            bf16x8 bh2 = *(const bf16x8*)&Bc[(32 + m) * 128 + ks];
            bf16x8 bh3 = *(const bf16x8*)&Bc[(48 + m) * 128 + ks];
            // TRANSPOSED: cand fragments as A, query fragment as B.
            acc0 = __builtin_amdgcn_mfma_f32_16x16x32_bf16(bh0, ah, acc0, 0, 0, 0);
            acc1 = __builtin_amdgcn_mfma_f32_16x16x32_bf16(bh1, ah, acc1, 0, 0, 0);
            acc2 = __builtin_amdgcn_mfma_f32_16x16x32_bf16(bh2, ah, acc2, 0, 0, 0);
            acc3 = __builtin_amdgcn_mfma_f32_16x16x32_bf16(bh3, ah, acc3, 0, 0, 0);
        }
        // no second barrier: prefetch targets the other buffer; Bc is stable
        // until every wave passes the NEXT loop-top barrier.

        // ---- in-register selection: lane holds D[cand][qglob] for 16 cands.
        // d = sq[cand] - 2*dot; sq[query] omitted (constant per lane's list).
        // Strict u64-key test (exact order); persistent 2-deep queue;
        // overflow passers insert immediately — every passer reaches ins12 once.
#pragma unroll
        for (int cg = 0; cg < 4; ++cg) {
            const f32x4 ac = (cg == 0) ? acc0 : (cg == 1) ? acc1
                           : (cg == 2) ? acc2 : acc3;
            const float4 s4 = *(const float4*)&sq[ct + cg * 16 + quad * 4];
#pragma unroll
            for (int reg = 0; reg < 4; ++reg) {
                const float sv = (reg == 0) ? s4.x : (reg == 1) ? s4.y
                               : (reg == 2) ? s4.z : s4.w;
                const float d = __builtin_fmaf(-2.f, ac[reg], sv);
                const int cgi = ct + cg * 16 + quad * 4 + reg;
                const u64 key = mkkey(d, cgi);
                const bool pass = (key < T.kb) && (cgi != qglob);
                if (pass) {
                    if (qn >= 2) {
                        ins12(T, key);
                    } else if (qn == 0) {
                        qk0 = key;
                    } else {
                        qk1 = key;
                    }
                    ++qn;
                }
            }
        }
        // flush only when some lane's queue is full — wave-uniform branch
        if (__any(qn >= 2)) {
            ins12(T, qk0);
            ins12(T, qk1);
            qk0 = qk1 = ~0ULL;
            qn = 0;
        }
        boff ^= 64 * 128;
    }

    // final queue flush (max-keys are no-ops), then merge the 4 partial
    // lists per query (lanes m, m+16, m+32, m+48 share query m)
    ins12(T, qk0);
    ins12(T, qk1);
    merge_shfl(T, 16);
    merge_shfl(T, 32);

    if (quad == 0) {
        unsigned short* cp_out = cand + (size_t)qglob * (NHALF * NCAND) + half * NCAND;
        cp_out[0]=(unsigned short)T.k0; cp_out[1]=(unsigned short)T.k1;
        cp_out[2]=(unsigned short)T.k2; cp_out[3]=(unsigned short)T.k3;
        cp_out[4]=(unsigned short)T.k4; cp_out[5]=(unsigned short)T.k5;
        cp_out[6]=(unsigned short)T.k6; cp_out[7]=(unsigned short)T.k7;
        cp_out[8]=(unsigned short)T.k8; cp_out[9]=(unsigned short)T.k9;
        cp_out[10]=(unsigned short)T.ka; cp_out[11]=(unsigned short)T.kb;
    }
}

// ---------------- Kernel 2.5: numpy-fp32-replica re-rank of 48 candidates ----------------
// 16 threads/point (3 cands each), u64-key shfl-merge of partial top-9s —
// top-k under the key order (== (d, idx) lex) is order-independent -> exact.
// dot: BLAS sgemm per-element rounding = ONE accumulator, sequential ascending-k FMA.
// d  : fl( fl(sq_i + sq_j) - fl(2*dot) ).
// DO NOT TOUCH the rounding order — verified exact vs reference (round 6, absmax 0.0).
__global__ __launch_bounds__(256) void refine_np_kernel(const float* __restrict__ x,
                                                        const float* __restrict__ sq,
                                                        const unsigned short* __restrict__ cand,
                                                        unsigned short* __restrict__ nbr) {
    const int gt = blockIdx.x * 256 + threadIdx.x;
    const int i = gt >> 4;         // point
    const int g = gt & (RG - 1);   // candidate group
    const float4* X4 = (const float4*)x;
    const float sqi = sq[i];

    int ci[RCAND];
#pragma unroll
    for (int m = 0; m < RCAND; ++m)
        ci[m] = (int)cand[i * (NHALF * NCAND) + g * RCAND + m];
    float dot[RCAND];
#pragma unroll
    for (int m = 0; m < RCAND; ++m) dot[m] = 0.f;
#pragma unroll 4
    for (int c4 = 0; c4 < 32; ++c4) {
        float4 xv = X4[(size_t)i * 32 + c4];
#pragma unroll
        for (int m = 0; m < RCAND; ++m) {
            float4 nv = X4[(size_t)ci[m] * 32 + c4];
            float a = dot[m];
            a = __builtin_fmaf(xv.x, nv.x, a);
            a = __builtin_fmaf(xv.y, nv.y, a);
            a = __builtin_fmaf(xv.z, nv.z, a);
            a = __builtin_fmaf(xv.w, nv.w, a);
            dot[m] = a;
        }
    }

    TopK9 T;
    T.k0=T.k1=T.k2=T.k3=T.k4=T.k5=T.k6=T.k7=T.k8 = ~0ULL;
#pragma unroll
    for (int m = 0; m < RCAND; ++m) {
        float s = __fadd_rn(sqi, sq[ci[m]]);
        float d = __fsub_rn(s, __fmul_rn(2.0f, dot[m]));
        ins9(T, mkkey(d, ci[m]));
    }

    // merge the 16 partial lists per point (lanes g^1,g^2,g^4,g^8 share point i)
    merge_shfl9(T, 1);
    merge_shfl9(T, 2);
    merge_shfl9(T, 4);
    merge_shfl9(T, 8);

    if (g == 0) {
        unsigned short* np = nbr + (size_t)i * KNN;
        np[0]=(unsigned short)T.k0; np[1]=(unsigned short)T.k1; np[2]=(unsigned short)T.k2;
        np[3]=(unsigned short)T.k3; np[4]=(unsigned short)T.k4; np[5]=(unsigned short)T.k5;
        np[6]=(unsigned short)T.k6; np[7]=(unsigned short)T.k7; np[8]=(unsigned short)T.k8;
    }
}

// ---------------- Kernel 3: rel-pos add + max-relative + concat-GEMM ----------------
// 1-wave blocks of 8 rows (grid 2048, 8 waves/CU): cat reads are broadcast and
// issued by ONE wave per block. Thread t owns cols {t, t+64, t+128, t+192};
// W read via Wt float4 along k. FMA order (c0 asc, k asc, bias first)
// identical to the original -> bit-identical output.
__global__ __launch_bounds__(64) void out_kernel(const float* __restrict__ x,
                                                 const float* __restrict__ tab,
                                                 const float* __restrict__ Wt,
                                                 const float* __restrict__ bias,
                                                 const unsigned short* __restrict__ nbr,
                                                 float* __restrict__ out) {
    __shared__ float cat[8][260];
    const int t = threadIdx.x;
    const int row0 = blockIdx.x * 8;
    {
        const int row = t >> 3;
        const int q = t & 7;
        const int i = row0 + row;
        const int rel_i = (i >> 7) - (i & 127) + 127;
        int nb[KNN], reln[KNN];
#pragma unroll
        for (int j = 0; j < KNN; ++j) {
            nb[j] = (int)nbr[i * KNN + j];
            reln[j] = (nb[j] >> 7) - (nb[j] & 127) + 127;
        }
        const float4* X4 = (const float4*)x;
        const float4* T4 = (const float4*)tab;
#pragma unroll
        for (int cc = 0; cc < 4; ++cc) {
            const int c4 = q * 4 + cc;
            float4 xv = X4[i * 32 + c4];
            float4 tv = T4[rel_i * 32 + c4];
            float4 xi;
            xi.x = xv.x + tv.x; xi.y = xv.y + tv.y; xi.z = xv.z + tv.z; xi.w = xv.w + tv.w;
            const float ninf = -__builtin_inff();
            float4 mx = {ninf, ninf, ninf, ninf};
#pragma unroll
            for (int j = 0; j < KNN; ++j) {
                float4 nv = X4[nb[j] * 32 + c4];
                float4 ntv = T4[reln[j] * 32 + c4];
                mx.x = fmaxf(mx.x, nv.x + ntv.x - xi.x);
                mx.y = fmaxf(mx.y, nv.y + ntv.y - xi.y);
                mx.z = fmaxf(mx.z, nv.z + ntv.z - xi.z);
                mx.w = fmaxf(mx.w, nv.w + ntv.w - xi.w);
            }
            *(float4*)&cat[row][c4 * 4] = xi;
            *(float4*)&cat[row][CH + c4 * 4] = mx;
        }
    }
    __syncthreads();

    float acc[8][4];
#pragma unroll
    for (int c = 0; c < 4; ++c) {
        const float bo = bias[t + 64 * c];
#pragma unroll
        for (int i = 0; i < 8; ++i) acc[i][c] = bo;
    }

    const float4* WT4 = (const float4*)Wt;   // Wt[col][k], k vectorized
#pragma unroll 2
    for (int c04 = 0; c04 < 64; ++c04) {     // c0 = 4*c04
        float4 wv0 = WT4[(size_t)(t +   0) * 64 + c04];
        float4 wv1 = WT4[(size_t)(t +  64) * 64 + c04];
        float4 wv2 = WT4[(size_t)(t + 128) * 64 + c04];
        float4 wv3 = WT4[(size_t)(t + 192) * 64 + c04];
#pragma unroll
        for (int i = 0; i < 8; ++i) {
            const float4 cv = *(const float4*)&cat[i][c04 * 4];
            acc[i][0] = fmaf(cv.x, wv0.x, acc[i][0]);
            acc[i][0] = fmaf(cv.y, wv0.y, acc[i][0]);
            acc[i][0] = fmaf(cv.z, wv0.z, acc[i][0]);
            acc[i][0] = fmaf(cv.w, wv0.w, acc[i][0]);
            acc[i][1] = fmaf(cv.x, wv1.x, acc[i][1]);
            acc[i][1] = fmaf(cv.y, wv1.y, acc[i][1]);
            acc[i][1] = fmaf(cv.z, wv1.z, acc[i][1]);
            acc[i][1] = fmaf(cv.w, wv1.w, acc[i][1]);
            acc[i][2] = fmaf(cv.x, wv2.x, acc[i][2]);
            acc[i][2] = fmaf(cv.y, wv2.y, acc[i][2]);
            acc[i][2] = fmaf(cv.z, wv2.z, acc[i][2]);
            acc[i][2] = fmaf(cv.w, wv2.w, acc[i][2]);
            acc[i][3] = fmaf(cv.x, wv3.x, acc[i][3]);
            acc[i][3] = fmaf(cv.y, wv3.y, acc[i][3]);
            acc[i][3] = fmaf(cv.z, wv3.z, acc[i][3]);
            acc[i][3] = fmaf(cv.w, wv3.w, acc[i][3]);
        }
    }

#pragma unroll
    for (int i = 0; i < 8; ++i) {
#pragma unroll
        for (int c = 0; c < 4; ++c) {
            out[(size_t)(row0 + i) * COUT + t + 64 * c] = acc[i][c];
        }
    }
}

extern "C" void kernel_launch(void* const* d_in, const int* in_sizes, int n_in,
                              void* d_out, int out_size, void* d_ws, size_t ws_size,
                              hipStream_t stream) {
    (void)in_sizes; (void)n_in; (void)out_size; (void)ws_size;
    const float* x = (const float*)d_in[0];
    const float* tab = (const float*)d_in[1];
    const float* W = (const float*)d_in[2];
    const float* b = (const float*)d_in[3];
    float* out = (float*)d_out;

    char* ws = (char*)d_ws;
    float* sq = (float*)ws;                                       // 64 KB
    unsigned short* nbr = (unsigned short*)(sq + NPTS);           // N*9 u16 = 288 KB
    float* Wt = (float*)(ws + 64 * 1024 + 288 * 1024);            // 256 KB
    // d_ws total 608 KiB < 1.375 MiB proven-safe (round 8)

    // d_out scratch (16 MB fp32): xhi 4 MB @0, cand 1.5 MB @4 MB.
    // Both recomputed every launch; out_kernel overwrites all of d_out last.
    short* xhi = (short*)d_out;
    unsigned short* cand = (unsigned short*)((char*)d_out + ((size_t)NPTS * CH * 2));

    sqnp_kernel<<<NPTS / 256, 256, 0, stream>>>(x, sq);
    split_kernel<<<NPTS * 16 / 256, 256, 0, stream>>>(x, xhi);
    wt_kernel<<<COUT, 2 * CH, 0, stream>>>(W, Wt);
    knn_kernel<<<dim3(NPTS / 64, NHALF), 256, 0, stream>>>(xhi, sq, cand);
    refine_np_kernel<<<NPTS * RG / 256, 256, 0, stream>>>(x, sq, cand, nbr);
    out_kernel<<<NPTS / 8, 64, 0, stream>>>(x, tab, Wt, b, nbr, out);
}